// Round 1
// baseline (4359.152 us; speedup 1.0000x reference)
//
#include <hip/hip_runtime.h>

#define TPB 256

__global__ void k_fill1(float* __restrict__ p, int n) {
  int i = blockIdx.x * blockDim.x + threadIdx.x;
  if (i < n) p[i] = 1.0f;
}

__global__ void k_deg_scatter(const int* __restrict__ dst, float* __restrict__ deg, int E) {
  int e = blockIdx.x * blockDim.x + threadIdx.x;
  if (e < E) atomicAdd(deg + dst[e], 1.0f);
}

__global__ void k_rsqrt_inplace(float* __restrict__ p, int n) {
  int i = blockIdx.x * blockDim.x + threadIdx.x;
  if (i < n) p[i] = rsqrtf(p[i]);
}

// Y[N, COUT] = X[N, 128] @ W[128, COUT].  W fully staged in LDS.
// 256 threads/block; each thread computes 8 contiguous output cols of one row.
template<int COUT>
__launch_bounds__(256)
__global__ void k_gemm128(const float* __restrict__ X, const float* __restrict__ W,
                          float* __restrict__ Y, int N) {
  constexpr int K = 128;
  constexpr int CG = COUT / 8;       // col-groups per row
  constexpr int ROWS = 256 / CG;     // rows per block
  constexpr int XSTR = K + 4;        // padded LDS row stride (floats), 132*4B = 16B-aligned
  __shared__ float Ws[K * COUT];
  __shared__ float Xs[ROWS * XSTR];
  const int tid = threadIdx.x;

  const float4* W4 = (const float4*)W;
  float4* Ws4 = (float4*)Ws;
  #pragma unroll
  for (int i = tid; i < K * COUT / 4; i += 256) Ws4[i] = W4[i];

  const int rb = blockIdx.x * ROWS;
  float4* Xs4 = (float4*)Xs;
  for (int i = tid; i < ROWS * (K / 4); i += 256) {
    int r = i / (K / 4), c = i % (K / 4);
    float4 v = make_float4(0.f, 0.f, 0.f, 0.f);
    if (rb + r < N) v = ((const float4*)(X + (size_t)(rb + r) * K))[c];
    Xs4[r * (XSTR / 4) + c] = v;
  }
  __syncthreads();

  const int lrow = tid / CG;
  const int cg = tid % CG;
  const int row = rb + lrow;
  float acc[8];
  #pragma unroll
  for (int j = 0; j < 8; ++j) acc[j] = 0.f;
  const float* xr = Xs + lrow * XSTR;
  #pragma unroll 4
  for (int k = 0; k < K; ++k) {
    float xv = xr[k];
    float4 w0 = Ws4[k * (COUT / 4) + cg * 2];
    float4 w1 = Ws4[k * (COUT / 4) + cg * 2 + 1];
    acc[0] = fmaf(xv, w0.x, acc[0]);
    acc[1] = fmaf(xv, w0.y, acc[1]);
    acc[2] = fmaf(xv, w0.z, acc[2]);
    acc[3] = fmaf(xv, w0.w, acc[3]);
    acc[4] = fmaf(xv, w1.x, acc[4]);
    acc[5] = fmaf(xv, w1.y, acc[5]);
    acc[6] = fmaf(xv, w1.z, acc[6]);
    acc[7] = fmaf(xv, w1.w, acc[7]);
  }
  if (row < N) {
    float4* y = (float4*)(Y + (size_t)row * COUT + cg * 8);
    y[0] = make_float4(acc[0], acc[1], acc[2], acc[3]);
    y[1] = make_float4(acc[4], acc[5], acc[6], acc[7]);
  }
}

// agg[i,c] = h[i,c]*dinv[i]^2 (self-loop init, also zero-fills agg);
// h[i,c] *= dinv[i] in place (pre-scaled gather operand).
template<int C>
__global__ void k_selfinit(float* __restrict__ h, const float* __restrict__ dinv,
                           float* __restrict__ agg, int N) {
  int i = blockIdx.x * blockDim.x + threadIdx.x;
  int total = N * (C / 4);
  if (i >= total) return;
  int node = i / (C / 4);
  float di = dinv[node];
  float4 v = ((const float4*)h)[i];
  float4 hs = make_float4(v.x * di, v.y * di, v.z * di, v.w * di);
  ((float4*)h)[i] = hs;
  ((float4*)agg)[i] = make_float4(hs.x * di, hs.y * di, hs.z * di, hs.w * di);
}

// agg[dst] += hs[src] * dinv[dst]   (hs already pre-scaled by dinv[src])
template<int C>
__global__ void k_scatter(const float* __restrict__ hs, const float* __restrict__ dinv,
                          const int* __restrict__ src, const int* __restrict__ dst,
                          float* __restrict__ agg, int E) {
  constexpr int LPE = C / 4;  // threads per edge (float4 chunks)
  long long t = (long long)blockIdx.x * blockDim.x + threadIdx.x;
  int e = (int)(t / LPE);
  if (e >= E) return;
  int c4 = (int)(t % LPE);
  int s = src[e], d = dst[e];
  float nd = dinv[d];
  float4 v = ((const float4*)(hs + (size_t)s * C))[c4];
  float* a = agg + (size_t)d * C + (size_t)c4 * 4;
  atomicAdd(a + 0, v.x * nd);
  atomicAdd(a + 1, v.y * nd);
  atomicAdd(a + 2, v.z * nd);
  atomicAdd(a + 3, v.w * nd);
}

template<int C>
__global__ void k_relu_bias(const float* __restrict__ agg, const float* __restrict__ b,
                            float* __restrict__ out, int N) {
  int i = blockIdx.x * blockDim.x + threadIdx.x;
  int total = N * (C / 4);
  if (i >= total) return;
  int c4 = i % (C / 4);
  float4 bb = ((const float4*)b)[c4];
  float4 v = ((const float4*)agg)[i];
  v.x = fmaxf(v.x + bb.x, 0.f);
  v.y = fmaxf(v.y + bb.y, 0.f);
  v.z = fmaxf(v.z + bb.z, 0.f);
  v.w = fmaxf(v.w + bb.w, 0.f);
  ((float4*)out)[i] = v;
}

extern "C" void kernel_launch(void* const* d_in, const int* in_sizes, int n_in,
                              void* d_out, int out_size, void* d_ws, size_t ws_size,
                              hipStream_t stream) {
  const float* x  = (const float*)d_in[0];
  const int*   ei = (const int*)d_in[1];
  const float* W1 = (const float*)d_in[2];
  const float* b1 = (const float*)d_in[3];
  const float* W2 = (const float*)d_in[4];
  const float* b2 = (const float*)d_in[5];

  const int Cin = 128, Chid = 128, Cout = 64;
  const int N = in_sizes[0] / Cin;
  const int E = in_sizes[1] / 2;
  const int* src = ei;
  const int* dst = ei + E;
  float* out = (float*)d_out;
  (void)n_in; (void)out_size; (void)ws_size; (void)Cout;

  // workspace layout: dinv[N] | A[N*128] | B[N*128]   (~103 MB)
  char* ws = (char*)d_ws;
  size_t off = 0;
  float* dinv = (float*)(ws + off); off += (((size_t)N * 4) + 255) & ~(size_t)255;
  float* A = (float*)(ws + off); off += (size_t)N * Chid * 4;
  float* B = (float*)(ws + off);

  const int nbN = (N + TPB - 1) / TPB;
  const int nbE = (E + TPB - 1) / TPB;

  // degree (shared by both layers)
  k_fill1<<<nbN, TPB, 0, stream>>>(dinv, N);
  k_deg_scatter<<<nbE, TPB, 0, stream>>>(dst, dinv, E);
  k_rsqrt_inplace<<<nbN, TPB, 0, stream>>>(dinv, N);

  // ---- layer 1: Cin=128 -> Chid=128 ----
  k_gemm128<128><<<(N + 15) / 16, 256, 0, stream>>>(x, W1, A, N);        // A = x@W1
  k_selfinit<128><<<(N * 32 + TPB - 1) / TPB, TPB, 0, stream>>>(A, dinv, B, N); // B = A*d^2, A *= d
  {
    long long total = (long long)E * 32;
    k_scatter<128><<<(int)((total + TPB - 1) / TPB), TPB, 0, stream>>>(A, dinv, src, dst, B, E);
  }
  k_relu_bias<128><<<(N * 32 + TPB - 1) / TPB, TPB, 0, stream>>>(B, b1, A, N);  // A = relu(B+b1)

  // ---- layer 2: Chid=128 -> Cout=64 ----
  k_gemm128<64><<<(N + 31) / 32, 256, 0, stream>>>(A, W2, B, N);         // B = A@W2
  k_selfinit<64><<<(N * 16 + TPB - 1) / TPB, TPB, 0, stream>>>(B, dinv, out, N); // out = B*d^2, B *= d
  {
    long long total = (long long)E * 16;
    k_scatter<64><<<(int)((total + TPB - 1) / TPB), TPB, 0, stream>>>(B, dinv, src, dst, out, E);
  }
  k_relu_bias<64><<<(N * 16 + TPB - 1) / TPB, TPB, 0, stream>>>(out, b2, out, N);
}

// Round 2
// 534.790 us; speedup vs baseline: 8.1511x; 8.1511x over previous
//
#include <hip/hip_runtime.h>

#define TPB 256
#define SCAN_B 256

// ---------- degree / CSR build ----------

__global__ void k_hist(const int* __restrict__ dst, int* __restrict__ cnt, int E) {
  int e = blockIdx.x * blockDim.x + threadIdx.x;
  if (e < E) atomicAdd(cnt + dst[e], 1);
}

__global__ void k_dinv_from_cnt(const int* __restrict__ cnt, float* __restrict__ dinv, int N) {
  int i = blockIdx.x * blockDim.x + threadIdx.x;
  if (i < N) dinv[i] = rsqrtf((float)(cnt[i] + 1));
}

// inclusive scan within 256-blocks; rowptr1 = rowptr+1 (rowptr[i+1] = partial inclusive)
__global__ void k_scanA(const int* __restrict__ cnt, int* __restrict__ rowptr1,
                        int* __restrict__ bsum, int N) {
  __shared__ int s[SCAN_B];
  int i = blockIdx.x * SCAN_B + threadIdx.x;
  int v = (i < N) ? cnt[i] : 0;
  s[threadIdx.x] = v;
  __syncthreads();
  for (int off = 1; off < SCAN_B; off <<= 1) {
    int t = (threadIdx.x >= (unsigned)off) ? s[threadIdx.x - off] : 0;
    __syncthreads();
    s[threadIdx.x] += t;
    __syncthreads();
  }
  if (i < N) rowptr1[i] = s[threadIdx.x];
  if (threadIdx.x == SCAN_B - 1) bsum[blockIdx.x] = s[SCAN_B - 1];
}

// single block, exclusive scan of block sums in place (nb <= 1024)
__global__ void k_scanB(int* __restrict__ bsum, int nb) {
  __shared__ int s[1024];
  int v = (threadIdx.x < (unsigned)nb) ? bsum[threadIdx.x] : 0;
  s[threadIdx.x] = v;
  __syncthreads();
  for (int off = 1; off < 1024; off <<= 1) {
    int t = (threadIdx.x >= (unsigned)off) ? s[threadIdx.x - off] : 0;
    __syncthreads();
    s[threadIdx.x] += t;
    __syncthreads();
  }
  if (threadIdx.x < (unsigned)nb) bsum[threadIdx.x] = s[threadIdx.x] - v;
}

__global__ void k_scanC(int* __restrict__ rowptr, const int* __restrict__ bsum, int N) {
  int i = blockIdx.x * SCAN_B + threadIdx.x;
  if (i < N) rowptr[i + 1] += bsum[blockIdx.x];
  if (i == 0) rowptr[0] = 0;
}

__global__ void k_copy_i32(int* __restrict__ d, const int* __restrict__ s, int n) {
  int i = blockIdx.x * blockDim.x + threadIdx.x;
  if (i < n) d[i] = s[i];
}

__global__ void k_fillcsr(const int* __restrict__ src, const int* __restrict__ dst,
                          int* __restrict__ wpos, int* __restrict__ col, int E) {
  int e = blockIdx.x * blockDim.x + threadIdx.x;
  if (e >= E) return;
  int p = atomicAdd(wpos + dst[e], 1);
  col[p] = src[e];
}

// ---------- GEMM: Y[N,COUT] = (X[N,128] @ W[128,COUT]) * dinv[row] ----------

template<int COUT>
__launch_bounds__(256)
__global__ void k_gemm128(const float* __restrict__ X, const float* __restrict__ W,
                          const float* __restrict__ dinv, float* __restrict__ Y, int N) {
  constexpr int K = 128;
  constexpr int CG = COUT / 8;
  constexpr int ROWS = 256 / CG;
  constexpr int XSTR = K + 4;
  __shared__ float Ws[K * COUT];
  __shared__ float Xs[ROWS * XSTR];
  const int tid = threadIdx.x;

  const float4* W4 = (const float4*)W;
  float4* Ws4 = (float4*)Ws;
  #pragma unroll
  for (int i = tid; i < K * COUT / 4; i += 256) Ws4[i] = W4[i];

  const int rb = blockIdx.x * ROWS;
  float4* Xs4 = (float4*)Xs;
  for (int i = tid; i < ROWS * (K / 4); i += 256) {
    int r = i / (K / 4), c = i % (K / 4);
    float4 v = make_float4(0.f, 0.f, 0.f, 0.f);
    if (rb + r < N) v = ((const float4*)(X + (size_t)(rb + r) * K))[c];
    Xs4[r * (XSTR / 4) + c] = v;
  }
  __syncthreads();

  const int lrow = tid / CG;
  const int cg = tid % CG;
  const int row = rb + lrow;
  float acc[8];
  #pragma unroll
  for (int j = 0; j < 8; ++j) acc[j] = 0.f;
  const float* xr = Xs + lrow * XSTR;
  #pragma unroll 4
  for (int k = 0; k < K; ++k) {
    float xv = xr[k];
    float4 w0 = Ws4[k * (COUT / 4) + cg * 2];
    float4 w1 = Ws4[k * (COUT / 4) + cg * 2 + 1];
    acc[0] = fmaf(xv, w0.x, acc[0]);
    acc[1] = fmaf(xv, w0.y, acc[1]);
    acc[2] = fmaf(xv, w0.z, acc[2]);
    acc[3] = fmaf(xv, w0.w, acc[3]);
    acc[4] = fmaf(xv, w1.x, acc[4]);
    acc[5] = fmaf(xv, w1.y, acc[5]);
    acc[6] = fmaf(xv, w1.z, acc[6]);
    acc[7] = fmaf(xv, w1.w, acc[7]);
  }
  if (row < N) {
    float ds = dinv[row];
    float4* y = (float4*)(Y + (size_t)row * COUT + cg * 8);
    y[0] = make_float4(acc[0] * ds, acc[1] * ds, acc[2] * ds, acc[3] * ds);
    y[1] = make_float4(acc[4] * ds, acc[5] * ds, acc[6] * ds, acc[7] * ds);
  }
}

// ---------- CSR gather-aggregate (one block of C threads per node) ----------
// out[i] = relu(dinv[i] * (hs[i] + sum_{j in nbr(i)} hs[j]) + bias)

template<int C>
__launch_bounds__(C)
__global__ void k_agg(const float* __restrict__ hs, const float* __restrict__ dinv,
                      const int* __restrict__ rowptr, const int* __restrict__ col,
                      const float* __restrict__ bias, float* __restrict__ out, int N) {
  const int node = blockIdx.x;
  const int tid = threadIdx.x;
  float acc = hs[(size_t)node * C + tid];
  const int beg = rowptr[node];
  const int end = rowptr[node + 1];
  __shared__ int nb[C];
  for (int base = beg; base < end; base += C) {
    int m = min(C, end - base);
    if (tid < m) nb[tid] = col[base + tid];
    __syncthreads();
    for (int k = 0; k < m; ++k) acc += hs[(size_t)nb[k] * C + tid];
    __syncthreads();
  }
  out[(size_t)node * C + tid] = fmaxf(fmaf(dinv[node], acc, bias[tid]), 0.f);
}

// ---------- fallback (atomic scatter) path, used only if ws too small ----------

__global__ void k_fill1(float* __restrict__ p, int n) {
  int i = blockIdx.x * blockDim.x + threadIdx.x;
  if (i < n) p[i] = 1.0f;
}
__global__ void k_deg_scatter(const int* __restrict__ dst, float* __restrict__ deg, int E) {
  int e = blockIdx.x * blockDim.x + threadIdx.x;
  if (e < E) atomicAdd(deg + dst[e], 1.0f);
}
__global__ void k_rsqrt_inplace(float* __restrict__ p, int n) {
  int i = blockIdx.x * blockDim.x + threadIdx.x;
  if (i < n) p[i] = rsqrtf(p[i]);
}
// agg init from prescaled hs: agg[i] = hs[i]*dinv[i]
template<int C>
__global__ void k_selfinit2(const float* __restrict__ hs, const float* __restrict__ dinv,
                            float* __restrict__ agg, int N) {
  int i = blockIdx.x * blockDim.x + threadIdx.x;
  int total = N * (C / 4);
  if (i >= total) return;
  int node = i / (C / 4);
  float di = dinv[node];
  float4 v = ((const float4*)hs)[i];
  ((float4*)agg)[i] = make_float4(v.x * di, v.y * di, v.z * di, v.w * di);
}
template<int C>
__global__ void k_scatter(const float* __restrict__ hs, const float* __restrict__ dinv,
                          const int* __restrict__ src, const int* __restrict__ dst,
                          float* __restrict__ agg, int E) {
  constexpr int LPE = C / 4;
  long long t = (long long)blockIdx.x * blockDim.x + threadIdx.x;
  int e = (int)(t / LPE);
  if (e >= E) return;
  int c4 = (int)(t % LPE);
  int s = src[e], d = dst[e];
  float nd = dinv[d];
  float4 v = ((const float4*)(hs + (size_t)s * C))[c4];
  float* a = agg + (size_t)d * C + (size_t)c4 * 4;
  atomicAdd(a + 0, v.x * nd);
  atomicAdd(a + 1, v.y * nd);
  atomicAdd(a + 2, v.z * nd);
  atomicAdd(a + 3, v.w * nd);
}
template<int C>
__global__ void k_relu_bias(const float* __restrict__ agg, const float* __restrict__ b,
                            float* __restrict__ out, int N) {
  int i = blockIdx.x * blockDim.x + threadIdx.x;
  int total = N * (C / 4);
  if (i >= total) return;
  int c4 = i % (C / 4);
  float4 bb = ((const float4*)b)[c4];
  float4 v = ((const float4*)agg)[i];
  v.x = fmaxf(v.x + bb.x, 0.f);
  v.y = fmaxf(v.y + bb.y, 0.f);
  v.z = fmaxf(v.z + bb.z, 0.f);
  v.w = fmaxf(v.w + bb.w, 0.f);
  ((float4*)out)[i] = v;
}

extern "C" void kernel_launch(void* const* d_in, const int* in_sizes, int n_in,
                              void* d_out, int out_size, void* d_ws, size_t ws_size,
                              hipStream_t stream) {
  const float* x  = (const float*)d_in[0];
  const int*   ei = (const int*)d_in[1];
  const float* W1 = (const float*)d_in[2];
  const float* b1 = (const float*)d_in[3];
  const float* W2 = (const float*)d_in[4];
  const float* b2 = (const float*)d_in[5];

  const int Cin = 128, Chid = 128;
  const int N = in_sizes[0] / Cin;
  const int E = in_sizes[1] / 2;
  const int* src = ei;
  const int* dst = ei + E;
  float* out = (float*)d_out;
  (void)n_in; (void)out_size;

  const int nbN = (N + TPB - 1) / TPB;
  const int nbE = (E + TPB - 1) / TPB;
  const int nbScan = (N + SCAN_B - 1) / SCAN_B;  // <= 1024 required

  // ---- workspace layout (CSR path) ----
  auto align = [](size_t v) { return (v + 511) & ~(size_t)511; };
  char* ws = (char*)d_ws;
  size_t off = 0;
  float* dinv   = (float*)(ws + off); off += align((size_t)N * 4);
  int*   cnt    = (int*)(ws + off);   off += align((size_t)N * 4);        // reused as wpos
  int*   rowptr = (int*)(ws + off);   off += align((size_t)(N + 1) * 4);
  int*   bsum   = (int*)(ws + off);   off += align((size_t)nbScan * 4);
  int*   col    = (int*)(ws + off);   off += align((size_t)E * 4);
  float* A      = (float*)(ws + off); off += (size_t)N * Chid * 4;
  float* B      = (float*)(ws + off); off += (size_t)N * Chid * 4;
  const bool csr_ok = (off <= ws_size) && (nbScan <= 1024);

  if (csr_ok) {
    // ---- build degree + CSR (shared by both layers) ----
    hipMemsetAsync(cnt, 0, (size_t)N * 4, stream);
    k_hist<<<nbE, TPB, 0, stream>>>(dst, cnt, E);
    k_dinv_from_cnt<<<nbN, TPB, 0, stream>>>(cnt, dinv, N);
    k_scanA<<<nbScan, SCAN_B, 0, stream>>>(cnt, rowptr + 1, bsum, N);
    k_scanB<<<1, 1024, 0, stream>>>(bsum, nbScan);
    k_scanC<<<nbScan, SCAN_B, 0, stream>>>(rowptr, bsum, N);
    k_copy_i32<<<nbN, TPB, 0, stream>>>(cnt, rowptr, N);                 // wpos = rowptr
    k_fillcsr<<<nbE, TPB, 0, stream>>>(src, dst, cnt, col, E);

    // ---- layer 1: 128 -> 128 ----
    k_gemm128<128><<<(N + 15) / 16, 256, 0, stream>>>(x, W1, dinv, A, N);   // A = (x@W1)*dinv
    k_agg<128><<<N, 128, 0, stream>>>(A, dinv, rowptr, col, b1, B, N);      // B = relu(...)
    // ---- layer 2: 128 -> 64 ----
    k_gemm128<64><<<(N + 31) / 32, 256, 0, stream>>>(B, W2, dinv, A, N);    // A = (B@W2)*dinv
    k_agg<64><<<N, 64, 0, stream>>>(A, dinv, rowptr, col, b2, out, N);
  } else {
    // ---- fallback: R1 atomic-scatter path (layout: dinv | A | B) ----
    size_t o2 = 0;
    float* dinvF = (float*)(ws + o2); o2 += align((size_t)N * 4);
    float* AF = (float*)(ws + o2);    o2 += (size_t)N * Chid * 4;
    float* BF = (float*)(ws + o2);

    k_fill1<<<nbN, TPB, 0, stream>>>(dinvF, N);
    k_deg_scatter<<<nbE, TPB, 0, stream>>>(dst, dinvF, E);
    k_rsqrt_inplace<<<nbN, TPB, 0, stream>>>(dinvF, N);

    k_gemm128<128><<<(N + 15) / 16, 256, 0, stream>>>(x, W1, dinvF, AF, N);
    k_selfinit2<128><<<(N * 32 + TPB - 1) / TPB, TPB, 0, stream>>>(AF, dinvF, BF, N);
    {
      long long total = (long long)E * 32;
      k_scatter<128><<<(int)((total + TPB - 1) / TPB), TPB, 0, stream>>>(AF, dinvF, src, dst, BF, E);
    }
    k_relu_bias<128><<<(N * 32 + TPB - 1) / TPB, TPB, 0, stream>>>(BF, b1, AF, N);

    k_gemm128<64><<<(N + 31) / 32, 256, 0, stream>>>(AF, W2, dinvF, BF, N);
    k_selfinit2<64><<<(N * 16 + TPB - 1) / TPB, TPB, 0, stream>>>(BF, dinvF, out, N);
    {
      long long total = (long long)E * 16;
      k_scatter<64><<<(int)((total + TPB - 1) / TPB), TPB, 0, stream>>>(BF, dinvF, src, dst, out, E);
    }
    k_relu_bias<64><<<(N * 16 + TPB - 1) / TPB, TPB, 0, stream>>>(out, b2, out, N);
  }
}

// Round 3
// 457.248 us; speedup vs baseline: 9.5335x; 1.1696x over previous
//
#include <hip/hip_runtime.h>

#define TPB 256
#define SCAN_B 256

typedef __attribute__((ext_vector_type(8))) short bf16x8;
typedef __attribute__((ext_vector_type(4))) float f32x4;

// ---------- fp32 -> bf16 hi/lo split ----------
__device__ inline void split1(float x, unsigned short& h, unsigned short& l) {
  unsigned xb = __float_as_uint(x);
  h = (unsigned short)(xb >> 16);                       // truncate-to-bf16
  float hf = __uint_as_float(xb & 0xFFFF0000u);
  float lf = x - hf;                                    // residual, |lf| <= 2^-9 |x|
  l = (unsigned short)(__float_as_uint(lf) >> 16);
}

__device__ inline void split4(const float4 v, ushort4& h, ushort4& l) {
  split1(v.x, h.x, l.x);
  split1(v.y, h.y, l.y);
  split1(v.z, h.z, l.z);
  split1(v.w, h.w, l.w);
}

// ---------- degree / CSR build ----------

__global__ void k_hist(const int* __restrict__ dst, int* __restrict__ cnt, int E) {
  int e = blockIdx.x * blockDim.x + threadIdx.x;
  if (e < E) atomicAdd(cnt + dst[e], 1);
}

__global__ void k_dinv_from_cnt(const int* __restrict__ cnt, float* __restrict__ dinv, int N) {
  int i = blockIdx.x * blockDim.x + threadIdx.x;
  if (i < N) dinv[i] = rsqrtf((float)(cnt[i] + 1));
}

__global__ void k_scanA(const int* __restrict__ cnt, int* __restrict__ rowptr1,
                        int* __restrict__ bsum, int N) {
  __shared__ int s[SCAN_B];
  int i = blockIdx.x * SCAN_B + threadIdx.x;
  int v = (i < N) ? cnt[i] : 0;
  s[threadIdx.x] = v;
  __syncthreads();
  for (int off = 1; off < SCAN_B; off <<= 1) {
    int t = (threadIdx.x >= (unsigned)off) ? s[threadIdx.x - off] : 0;
    __syncthreads();
    s[threadIdx.x] += t;
    __syncthreads();
  }
  if (i < N) rowptr1[i] = s[threadIdx.x];
  if (threadIdx.x == SCAN_B - 1) bsum[blockIdx.x] = s[SCAN_B - 1];
}

__global__ void k_scanB(int* __restrict__ bsum, int nb) {
  __shared__ int s[1024];
  int v = (threadIdx.x < (unsigned)nb) ? bsum[threadIdx.x] : 0;
  s[threadIdx.x] = v;
  __syncthreads();
  for (int off = 1; off < 1024; off <<= 1) {
    int t = (threadIdx.x >= (unsigned)off) ? s[threadIdx.x - off] : 0;
    __syncthreads();
    s[threadIdx.x] += t;
    __syncthreads();
  }
  if (threadIdx.x < (unsigned)nb) bsum[threadIdx.x] = s[threadIdx.x] - v;
}

__global__ void k_scanC(int* __restrict__ rowptr, const int* __restrict__ bsum, int N) {
  int i = blockIdx.x * SCAN_B + threadIdx.x;
  if (i < N) rowptr[i + 1] += bsum[blockIdx.x];
  if (i == 0) rowptr[0] = 0;
}

__global__ void k_copy_i32(int* __restrict__ d, const int* __restrict__ s, int n) {
  int i = blockIdx.x * blockDim.x + threadIdx.x;
  if (i < n) d[i] = s[i];
}

__global__ void k_fillcsr(const int* __restrict__ src, const int* __restrict__ dst,
                          int* __restrict__ wpos, int* __restrict__ col, int E) {
  int e = blockIdx.x * blockDim.x + threadIdx.x;
  if (e >= E) return;
  int p = atomicAdd(wpos + dst[e], 1);
  col[p] = src[e];
}

// ---------- W prep: W[K][C] f32 -> Wt_hi/lo[C][K] bf16 (transposed + split) ----------
__global__ void k_prep_wt(const float* __restrict__ W, unsigned short* __restrict__ Wh,
                          unsigned short* __restrict__ Wl, int K, int C) {
  int i = blockIdx.x * blockDim.x + threadIdx.x;
  if (i >= K * C) return;
  int k = i / C, c = i % C;
  unsigned short h, l;
  split1(W[i], h, l);
  Wh[(size_t)c * K + k] = h;
  Wl[(size_t)c * K + k] = l;
}

// ---------- MFMA GEMM: Y[N,COUT] = (X[N,128] @ W[128,COUT]) * dinv[row] ----------
// split-bf16 (3 mfma) for fp32-grade accuracy. A & W LDS tiles XOR-swizzled
// (byte ^= (row&7)<<4) to kill the 32-way row-stride-256B ds_read_b128 conflict.
template<int COUT>
__launch_bounds__(512)
__global__ void k_gemm_mfma(const float* __restrict__ X, const unsigned short* __restrict__ Wh,
                            const unsigned short* __restrict__ Wl, const float* __restrict__ dinv,
                            float* __restrict__ Y, int N) {
  constexpr int K = 128;
  constexpr int BM = 128;
  constexpr int WCOL = COUT / 2;      // cols per wave (2 col-groups of waves)
  constexpr int NFRAG = WCOL / 16;    // 4 (COUT=128) or 2 (COUT=64)
  __shared__ unsigned short Ah[BM * K], Al[BM * K];
  __shared__ unsigned short Wsh[COUT * K], Wsl[COUT * K];

  const int tid = threadIdx.x;
  const int rb = blockIdx.x * BM;

  // stage W (already bf16 [COUT][K], 256B rows) with swizzle, 16B chunks
  {
    const uint4* gh = (const uint4*)Wh;
    const uint4* gl = (const uint4*)Wl;
    for (int i = tid; i < COUT * 16; i += 512) {
      int r = i >> 4, c = i & 15;
      int byte = r * 256 + ((c * 16) ^ ((r & 7) << 4));
      *(uint4*)((char*)Wsh + byte) = gh[i];
      *(uint4*)((char*)Wsl + byte) = gl[i];
    }
  }
  // stage A: load f32 float4, split to bf16 hi/lo, swizzled 8B writes
  {
    for (int i = tid; i < BM * 32; i += 512) {
      int r = i >> 5, c4 = i & 31;
      int g = rb + r;
      if (g < N) {
        float4 v = ((const float4*)(X + (size_t)g * K))[c4];
        ushort4 h, l;
        split4(v, h, l);
        int byte = r * 256 + ((c4 * 8) ^ ((r & 7) << 4));
        *(ushort4*)((char*)Ah + byte) = h;
        *(ushort4*)((char*)Al + byte) = l;
      }
      // rows >= N: LDS left stale; their outputs are never stored.
    }
  }
  __syncthreads();

  const int wid = tid >> 6, lane = tid & 63;
  const int wm = wid & 3;             // row group (32 rows)
  const int wn = wid >> 2;            // col group (WCOL cols)
  const int RB = wm * 32;
  const int CB = wn * WCOL;
  const int l15 = lane & 15, l4 = lane >> 4;
  const int xs = (l15 & 7) << 4;      // swizzle XOR (row&7 == l15&7 for all frag rows)

  f32x4 acc[2][NFRAG];
  #pragma unroll
  for (int m = 0; m < 2; ++m)
    #pragma unroll
    for (int n = 0; n < NFRAG; ++n)
      acc[m][n] = (f32x4){0.f, 0.f, 0.f, 0.f};

  #pragma unroll
  for (int ks = 0; ks < 4; ++ks) {
    const int cbx = (ks * 64 + l4 * 16) ^ xs;   // byte col within 256B row
    bf16x8 a0h = *(const bf16x8*)((const char*)Ah + (RB + l15) * 256 + cbx);
    bf16x8 a0l = *(const bf16x8*)((const char*)Al + (RB + l15) * 256 + cbx);
    bf16x8 a1h = *(const bf16x8*)((const char*)Ah + (RB + 16 + l15) * 256 + cbx);
    bf16x8 a1l = *(const bf16x8*)((const char*)Al + (RB + 16 + l15) * 256 + cbx);
    #pragma unroll
    for (int n = 0; n < NFRAG; ++n) {
      const int wr = CB + n * 16 + l15;
      bf16x8 bh = *(const bf16x8*)((const char*)Wsh + wr * 256 + cbx);
      bf16x8 bl = *(const bf16x8*)((const char*)Wsl + wr * 256 + cbx);
      acc[0][n] = __builtin_amdgcn_mfma_f32_16x16x32_bf16(a0h, bh, acc[0][n], 0, 0, 0);
      acc[0][n] = __builtin_amdgcn_mfma_f32_16x16x32_bf16(a0h, bl, acc[0][n], 0, 0, 0);
      acc[0][n] = __builtin_amdgcn_mfma_f32_16x16x32_bf16(a0l, bh, acc[0][n], 0, 0, 0);
      acc[1][n] = __builtin_amdgcn_mfma_f32_16x16x32_bf16(a1h, bh, acc[1][n], 0, 0, 0);
      acc[1][n] = __builtin_amdgcn_mfma_f32_16x16x32_bf16(a1h, bl, acc[1][n], 0, 0, 0);
      acc[1][n] = __builtin_amdgcn_mfma_f32_16x16x32_bf16(a1l, bh, acc[1][n], 0, 0, 0);
    }
  }

  // epilogue: D row = (lane>>4)*4 + reg, col = lane&15 (m89-verified)
  #pragma unroll
  for (int m = 0; m < 2; ++m) {
    #pragma unroll
    for (int q = 0; q < 4; ++q) {
      int row = rb + RB + m * 16 + l4 * 4 + q;
      if (row < N) {
        float dv = dinv[row];
        float* yr = Y + (size_t)row * COUT + CB + l15;
        #pragma unroll
        for (int n = 0; n < NFRAG; ++n) yr[n * 16] = acc[m][n][q] * dv;
      }
    }
  }
}

// ---------- vector GEMM (fallback path only) ----------
template<int COUT>
__launch_bounds__(256)
__global__ void k_gemm128(const float* __restrict__ X, const float* __restrict__ W,
                          const float* __restrict__ dinv, float* __restrict__ Y, int N) {
  constexpr int K = 128;
  constexpr int CG = COUT / 8;
  constexpr int ROWS = 256 / CG;
  constexpr int XSTR = K + 4;
  __shared__ float Ws[K * COUT];
  __shared__ float Xs[ROWS * XSTR];
  const int tid = threadIdx.x;

  const float4* W4 = (const float4*)W;
  float4* Ws4 = (float4*)Ws;
  #pragma unroll
  for (int i = tid; i < K * COUT / 4; i += 256) Ws4[i] = W4[i];

  const int rb = blockIdx.x * ROWS;
  float4* Xs4 = (float4*)Xs;
  for (int i = tid; i < ROWS * (K / 4); i += 256) {
    int r = i / (K / 4), c = i % (K / 4);
    float4 v = make_float4(0.f, 0.f, 0.f, 0.f);
    if (rb + r < N) v = ((const float4*)(X + (size_t)(rb + r) * K))[c];
    Xs4[r * (XSTR / 4) + c] = v;
  }
  __syncthreads();

  const int lrow = tid / CG;
  const int cg = tid % CG;
  const int row = rb + lrow;
  float acc[8];
  #pragma unroll
  for (int j = 0; j < 8; ++j) acc[j] = 0.f;
  const float* xr = Xs + lrow * XSTR;
  #pragma unroll 4
  for (int k = 0; k < K; ++k) {
    float xv = xr[k];
    float4 w0 = Ws4[k * (COUT / 4) + cg * 2];
    float4 w1 = Ws4[k * (COUT / 4) + cg * 2 + 1];
    acc[0] = fmaf(xv, w0.x, acc[0]);
    acc[1] = fmaf(xv, w0.y, acc[1]);
    acc[2] = fmaf(xv, w0.z, acc[2]);
    acc[3] = fmaf(xv, w0.w, acc[3]);
    acc[4] = fmaf(xv, w1.x, acc[4]);
    acc[5] = fmaf(xv, w1.y, acc[5]);
    acc[6] = fmaf(xv, w1.z, acc[6]);
    acc[7] = fmaf(xv, w1.w, acc[7]);
  }
  if (row < N) {
    float ds = dinv[row];
    float4* y = (float4*)(Y + (size_t)row * COUT + cg * 8);
    y[0] = make_float4(acc[0] * ds, acc[1] * ds, acc[2] * ds, acc[3] * ds);
    y[1] = make_float4(acc[4] * ds, acc[5] * ds, acc[6] * ds, acc[7] * ds);
  }
}

// ---------- CSR gather-aggregate ----------
template<int C>
__launch_bounds__(C)
__global__ void k_agg(const float* __restrict__ hs, const float* __restrict__ dinv,
                      const int* __restrict__ rowptr, const int* __restrict__ col,
                      const float* __restrict__ bias, float* __restrict__ out, int N) {
  const int node = blockIdx.x;
  const int tid = threadIdx.x;
  float acc = hs[(size_t)node * C + tid];
  const int beg = rowptr[node];
  const int end = rowptr[node + 1];
  __shared__ int nb[C];
  for (int base = beg; base < end; base += C) {
    int m = min(C, end - base);
    if (tid < m) nb[tid] = col[base + tid];
    __syncthreads();
    for (int k = 0; k < m; ++k) acc += hs[(size_t)nb[k] * C + tid];
    __syncthreads();
  }
  out[(size_t)node * C + tid] = fmaxf(fmaf(dinv[node], acc, bias[tid]), 0.f);
}

// ---------- fallback (atomic scatter) kernels ----------
__global__ void k_fill1(float* __restrict__ p, int n) {
  int i = blockIdx.x * blockDim.x + threadIdx.x;
  if (i < n) p[i] = 1.0f;
}
__global__ void k_deg_scatter(const int* __restrict__ dst, float* __restrict__ deg, int E) {
  int e = blockIdx.x * blockDim.x + threadIdx.x;
  if (e < E) atomicAdd(deg + dst[e], 1.0f);
}
__global__ void k_rsqrt_inplace(float* __restrict__ p, int n) {
  int i = blockIdx.x * blockDim.x + threadIdx.x;
  if (i < n) p[i] = rsqrtf(p[i]);
}
template<int C>
__global__ void k_selfinit2(const float* __restrict__ hs, const float* __restrict__ dinv,
                            float* __restrict__ agg, int N) {
  int i = blockIdx.x * blockDim.x + threadIdx.x;
  int total = N * (C / 4);
  if (i >= total) return;
  int node = i / (C / 4);
  float di = dinv[node];
  float4 v = ((const float4*)hs)[i];
  ((float4*)agg)[i] = make_float4(v.x * di, v.y * di, v.z * di, v.w * di);
}
template<int C>
__global__ void k_scatter(const float* __restrict__ hs, const float* __restrict__ dinv,
                          const int* __restrict__ src, const int* __restrict__ dst,
                          float* __restrict__ agg, int E) {
  constexpr int LPE = C / 4;
  long long t = (long long)blockIdx.x * blockDim.x + threadIdx.x;
  int e = (int)(t / LPE);
  if (e >= E) return;
  int c4 = (int)(t % LPE);
  int s = src[e], d = dst[e];
  float nd = dinv[d];
  float4 v = ((const float4*)(hs + (size_t)s * C))[c4];
  float* a = agg + (size_t)d * C + (size_t)c4 * 4;
  atomicAdd(a + 0, v.x * nd);
  atomicAdd(a + 1, v.y * nd);
  atomicAdd(a + 2, v.z * nd);
  atomicAdd(a + 3, v.w * nd);
}
template<int C>
__global__ void k_relu_bias(const float* __restrict__ agg, const float* __restrict__ b,
                            float* __restrict__ out, int N) {
  int i = blockIdx.x * blockDim.x + threadIdx.x;
  int total = N * (C / 4);
  if (i >= total) return;
  int c4 = i % (C / 4);
  float4 bb = ((const float4*)b)[c4];
  float4 v = ((const float4*)agg)[i];
  v.x = fmaxf(v.x + bb.x, 0.f);
  v.y = fmaxf(v.y + bb.y, 0.f);
  v.z = fmaxf(v.z + bb.z, 0.f);
  v.w = fmaxf(v.w + bb.w, 0.f);
  ((float4*)out)[i] = v;
}

extern "C" void kernel_launch(void* const* d_in, const int* in_sizes, int n_in,
                              void* d_out, int out_size, void* d_ws, size_t ws_size,
                              hipStream_t stream) {
  const float* x  = (const float*)d_in[0];
  const int*   ei = (const int*)d_in[1];
  const float* W1 = (const float*)d_in[2];
  const float* b1 = (const float*)d_in[3];
  const float* W2 = (const float*)d_in[4];
  const float* b2 = (const float*)d_in[5];

  const int Cin = 128, Chid = 128, Cout2 = 64;
  const int N = in_sizes[0] / Cin;
  const int E = in_sizes[1] / 2;
  const int* src = ei;
  const int* dst = ei + E;
  float* out = (float*)d_out;
  (void)n_in; (void)out_size;

  const int nbN = (N + TPB - 1) / TPB;
  const int nbE = (E + TPB - 1) / TPB;
  const int nbScan = (N + SCAN_B - 1) / SCAN_B;  // <= 1024 required
  const int nT = (N + 127) / 128;                // GEMM row tiles

  auto align = [](size_t v) { return (v + 511) & ~(size_t)511; };
  char* ws = (char*)d_ws;
  size_t off = 0;
  float* dinv   = (float*)(ws + off); off += align((size_t)N * 4);
  int*   cnt    = (int*)(ws + off);   off += align((size_t)N * 4);
  int*   rowptr = (int*)(ws + off);   off += align((size_t)(N + 1) * 4);
  int*   bsum   = (int*)(ws + off);   off += align((size_t)nbScan * 4);
  unsigned short* wt1h = (unsigned short*)(ws + off); off += align((size_t)Cin * Chid * 2);
  unsigned short* wt1l = (unsigned short*)(ws + off); off += align((size_t)Cin * Chid * 2);
  unsigned short* wt2h = (unsigned short*)(ws + off); off += align((size_t)Chid * Cout2 * 2);
  unsigned short* wt2l = (unsigned short*)(ws + off); off += align((size_t)Chid * Cout2 * 2);
  int*   col    = (int*)(ws + off);   off += align((size_t)E * 4);
  float* A      = (float*)(ws + off); off += (size_t)N * Chid * 4;
  float* B      = (float*)(ws + off); off += (size_t)N * Chid * 4;
  const bool csr_ok = (off <= ws_size) && (nbScan <= 1024);

  if (csr_ok) {
    // ---- degree + CSR (shared by both layers) ----
    hipMemsetAsync(cnt, 0, (size_t)N * 4, stream);
    k_hist<<<nbE, TPB, 0, stream>>>(dst, cnt, E);
    k_dinv_from_cnt<<<nbN, TPB, 0, stream>>>(cnt, dinv, N);
    k_scanA<<<nbScan, SCAN_B, 0, stream>>>(cnt, rowptr + 1, bsum, N);
    k_scanB<<<1, 1024, 0, stream>>>(bsum, nbScan);
    k_scanC<<<nbScan, SCAN_B, 0, stream>>>(rowptr, bsum, N);
    k_copy_i32<<<nbN, TPB, 0, stream>>>(cnt, rowptr, N);
    k_fillcsr<<<nbE, TPB, 0, stream>>>(src, dst, cnt, col, E);

    // ---- W prep (transpose + bf16 split) ----
    k_prep_wt<<<(Cin * Chid + TPB - 1) / TPB, TPB, 0, stream>>>(W1, wt1h, wt1l, Cin, Chid);
    k_prep_wt<<<(Chid * Cout2 + TPB - 1) / TPB, TPB, 0, stream>>>(W2, wt2h, wt2l, Chid, Cout2);

    // ---- layer 1: 128 -> 128 ----
    k_gemm_mfma<128><<<nT, 512, 0, stream>>>(x, wt1h, wt1l, dinv, A, N);  // A = (x@W1)*dinv
    k_agg<128><<<N, 128, 0, stream>>>(A, dinv, rowptr, col, b1, B, N);    // B = relu(...)
    // ---- layer 2: 128 -> 64 ----
    k_gemm_mfma<64><<<nT, 512, 0, stream>>>(B, wt2h, wt2l, dinv, A, N);   // A = (B@W2)*dinv
    k_agg<64><<<N, 64, 0, stream>>>(A, dinv, rowptr, col, b2, out, N);
  } else {
    // ---- fallback: atomic-scatter path ----
    size_t o2 = 0;
    float* dinvF = (float*)(ws + o2); o2 += align((size_t)N * 4);
    float* AF = (float*)(ws + o2);    o2 += (size_t)N * Chid * 4;
    float* BF = (float*)(ws + o2);

    k_fill1<<<nbN, TPB, 0, stream>>>(dinvF, N);
    k_deg_scatter<<<nbE, TPB, 0, stream>>>(dst, dinvF, E);
    k_rsqrt_inplace<<<nbN, TPB, 0, stream>>>(dinvF, N);

    k_gemm128<128><<<(N + 15) / 16, 256, 0, stream>>>(x, W1, dinvF, AF, N);
    k_selfinit2<128><<<(N * 32 + TPB - 1) / TPB, TPB, 0, stream>>>(AF, dinvF, BF, N);
    {
      long long total = (long long)E * 32;
      k_scatter<128><<<(int)((total + TPB - 1) / TPB), TPB, 0, stream>>>(AF, dinvF, src, dst, BF, E);
    }
    k_relu_bias<128><<<(N * 32 + TPB - 1) / TPB, TPB, 0, stream>>>(BF, b1, AF, N);

    k_gemm128<64><<<(N + 31) / 32, 256, 0, stream>>>(AF, W2, dinvF, BF, N);
    k_selfinit2<64><<<(N * 16 + TPB - 1) / TPB, TPB, 0, stream>>>(BF, dinvF, out, N);
    {
      long long total = (long long)E * 16;
      k_scatter<64><<<(int)((total + TPB - 1) / TPB), TPB, 0, stream>>>(BF, dinvF, src, dst, out, E);
    }
    k_relu_bias<64><<<(N * 16 + TPB - 1) / TPB, TPB, 0, stream>>>(out, b2, out, N);
  }
}